// Round 8
// baseline (8674.309 us; speedup 1.0000x reference)
//
#include <hip/hip_runtime.h>
#include <hip/hip_bf16.h>

// ---------------------------------------------------------------------------
// TransportOperator: FISTA sparse coding through block-diag expm + transport.
// B=256, D=512, K=8, M=64, N=64.  20 FISTA iters, lr=0.01, lambda=0.05.
//
// R7 lesson: cooperative launch (full-coresidency barrier) is rejected at
// launch time -> mega-kernel impossible.  R8: cut dispatches 84->44 with the
// DEADLOCK-FREE work-then-spin ticket pattern (R3/R4-validated cross-XCD):
// one fused dispatch runs krylov<6> (2048 wgs) -> [ticket] -> gemm2 partials
// (wgs 0..255) -> [ticket] -> fista prox (wgs 0..63).  Every wg signals only
// AFTER its own work, so the counters always reach target under any
// occupancy.  gemm1 stays a separate dispatch (fusing it would need
// spin-before-work => deadlock risk).
// ---------------------------------------------------------------------------

typedef __attribute__((ext_vector_type(8))) short bf16x8;
typedef __attribute__((ext_vector_type(4))) float f32x4;
typedef unsigned short ushort_t;
typedef unsigned int uint_t;

__device__ __constant__ float INVF[20] = {
    1.0f, 1.0f, 0.5f, 1.6666666666666666e-1f, 4.1666666666666664e-2f,
    8.333333333333333e-3f, 1.3888888888888889e-3f, 1.984126984126984e-4f,
    2.48015873015873e-5f, 2.7557319223985893e-6f, 2.755731922398589e-7f,
    2.505210838544172e-8f, 2.08767569878681e-9f, 1.6059043836821613e-10f,
    1.1470745597729725e-11f, 7.647163731819816e-13f, 4.779477332387385e-14f,
    2.8114572543455206e-15f, 1.5619206968586225e-16f, 8.22063524662433e-18f};

__device__ __forceinline__ ushort_t f2b(float x) {
    uint_t u = __float_as_uint(x);
    uint_t r = u + 0x7FFFu + ((u >> 16) & 1u);   // RNE
    return (ushort_t)(r >> 16);
}
__device__ __forceinline__ float b2f(ushort_t h) {
    return __uint_as_float((uint_t)h << 16);
}

// quad sum via DPP (VALU pipe, no LDS ops)
__device__ __forceinline__ float qsum4(float s) {
    int a = __builtin_amdgcn_update_dpp(0, __float_as_int(s), 0xB1, 0xF, 0xF, true);
    s += __int_as_float(a);                       // xor 1
    int b = __builtin_amdgcn_update_dpp(0, __float_as_int(s), 0x4E, 0xF, 0xF, true);
    s += __int_as_float(b);                       // xor 2
    return s;
}

struct KryS { float V[8][64]; float U[8][64]; float zz[64]; };
union FusedSm { KryS kry; float lg[64 * 68]; };   // 17408 B

// signal: all threads' prior global stores device-visible, then +1 (tid 0)
__device__ __forceinline__ void ticket_sig(uint_t* c, int tid) {
    __threadfence();
    __syncthreads();
    if (tid == 0)
        __hip_atomic_fetch_add(c, 1u, __ATOMIC_RELEASE, __HIP_MEMORY_SCOPE_AGENT);
}
// wait until *c == target, then make producers' stores visible to all threads
__device__ __forceinline__ void ticket_wait(uint_t* c, uint_t target, int tid) {
    if (tid == 0) {
        while (__hip_atomic_load(c, __ATOMIC_ACQUIRE,
                                 __HIP_MEMORY_SCOPE_AGENT) < target)
            __builtin_amdgcn_s_sleep(2);
    }
    __syncthreads();
    __threadfence();
}

// --- one-time: psi fp32 -> psiB [k][m][uv] bf16 and psiT [j=k*4096+uv][m] --
__global__ __launch_bounds__(256) void prep_k(const float* __restrict__ psi,
                                              ushort_t* __restrict__ psiB,
                                              ushort_t* __restrict__ psiT) {
    int base = blockIdx.x * 2048 + threadIdx.x;
    for (int i = 0; i < 8; ++i) {
        int e = base + i * 256;                // e in [0, 2097152)
        float v = psi[e];
        ushort_t h = f2b(v);
        psiB[e] = h;
        int k = e >> 18;
        int r = e & 262143;
        int m = r >> 12;
        int uv = r & 4095;
        psiT[(size_t)k * 262144 + (size_t)uv * 64 + m] = h;
    }
}

// --- GEMM1: T[b][j] = sum_m y[b,m] * psiT[j,m].  D-rows <-> j. -------------
// grid 1024 = 512 j-windows x 2 b-halves (128 b).  18 KB LDS.
__global__ __launch_bounds__(256) void gemm1_k(const ushort_t* __restrict__ ybf,
                                               const ushort_t* __restrict__ psiT,
                                               ushort_t* __restrict__ Tbf) {
    __shared__ __align__(16) ushort_t Ls[128 * 72];   // [b 128][j 64] swizzled
    int wg = blockIdx.x;
    int j0 = (wg & 511) * 64;
    int bt = wg >> 9;                   // 0..1
    int tid = threadIdx.x;
    int wave = tid >> 6, lane = tid & 63;
    int rowi = lane & 15, q = lane >> 4;
    int b0w = bt * 128 + wave * 32;

    f32x4 acc[4][2];
    const f32x4 zero = {0.f, 0.f, 0.f, 0.f};
    for (int ta = 0; ta < 4; ++ta)
        for (int tb = 0; tb < 2; ++tb) acc[ta][tb] = zero;

    for (int ks = 0; ks < 2; ++ks) {
        bf16x8 a[4], bb[2];
        for (int ta = 0; ta < 4; ++ta)
            a[ta] = *(const bf16x8*)(psiT + (size_t)(j0 + ta * 16 + rowi) * 64 +
                                     ks * 32 + q * 8);
        for (int tb = 0; tb < 2; ++tb)
            bb[tb] = *(const bf16x8*)(ybf + (size_t)(b0w + tb * 16 + rowi) * 64 +
                                      ks * 32 + q * 8);
        for (int ta = 0; ta < 4; ++ta)
            for (int tb = 0; tb < 2; ++tb)
                acc[ta][tb] = __builtin_amdgcn_mfma_f32_16x16x32_bf16(
                    a[ta], bb[tb], acc[ta][tb], 0, 0, 0);
    }
    for (int ta = 0; ta < 4; ++ta)
        for (int tb = 0; tb < 2; ++tb) {
            int bl = wave * 32 + tb * 16 + rowi;      // local b in [0,128)
            int jl = ta * 16 + q * 4;
            uint_t lo = (uint_t)f2b(acc[ta][tb][0]) | ((uint_t)f2b(acc[ta][tb][1]) << 16);
            uint_t hi = (uint_t)f2b(acc[ta][tb][2]) | ((uint_t)f2b(acc[ta][tb][3]) << 16);
            int idx = bl * 72 + ((((jl >> 3) + 2 * bl) & 7) << 3) + (jl & 7);
            *(uint2*)&Ls[idx] = make_uint2(lo, hi);
        }
    __syncthreads();
    for (int pass = 0; pass < 4; ++pass) {
        int b = pass * 32 + (tid >> 3);               // local b
        int ch = tid & 7;
        uint4 v = *(const uint4*)&Ls[b * 72 + ch * 8];
        int x = (ch - 2 * b) & 7;
        *(uint4*)(Tbf + (size_t)(bt * 128 + b) * 32768 + j0 + x * 8) = v;
    }
}

// --- krylov unit for one (b,k); GRAD writes O (bf16) over T, else fp32 out -
template <int NT, bool GRAD>
__device__ __forceinline__ void kry_one(int bid, ushort_t* __restrict__ TO,
                                        const float* __restrict__ z0,
                                        const float* __restrict__ z1,
                                        float* __restrict__ out,
                                        KryS& S, int tid) {
    int b = bid >> 3, k = bid & 7;
    int row = tid >> 2, p = tid & 3, c0 = p * 16;

    const ushort_t* tbase = TO + (size_t)bid * 4096;
    float rowT[16];
    {
        uint4 ra = *(const uint4*)(tbase + row * 64 + c0);
        uint4 rb = *(const uint4*)(tbase + row * 64 + c0 + 8);
        uint_t wv[8] = {ra.x, ra.y, ra.z, ra.w, rb.x, rb.y, rb.z, rb.w};
        for (int i = 0; i < 8; ++i) {
            rowT[2 * i]     = __uint_as_float(wv[i] << 16);
            rowT[2 * i + 1] = __uint_as_float(wv[i] & 0xFFFF0000u);
        }
    }
    float colT[16];
    if (GRAD) {
#pragma unroll
        for (int i = 0; i < 16; ++i) colT[i] = b2f(tbase[(c0 + i) * 64 + row]);
    }
    if (tid < 64) {
        S.V[0][tid] = z0[(size_t)b * 512 + k * 64 + tid];
        if (GRAD) S.zz[tid] = z1[(size_t)b * 512 + k * 64 + tid];
    }
    __syncthreads();

    // v series
    for (int l = 1; l < NT; ++l) {
        const f32x4* vp = (const f32x4*)&S.V[l - 1][c0];
        f32x4 v0 = vp[0], v1 = vp[1], v2 = vp[2], v3 = vp[3];
        float s0 = 0.f, s1 = 0.f, s2 = 0.f, s3 = 0.f;
#pragma unroll
        for (int i = 0; i < 4; ++i) {
            s0 = fmaf(rowT[i], v0[i], s0);
            s1 = fmaf(rowT[4 + i], v1[i], s1);
            s2 = fmaf(rowT[8 + i], v2[i], s2);
            s3 = fmaf(rowT[12 + i], v3[i], s3);
        }
        float s = qsum4((s0 + s1) + (s2 + s3));
        if (p == 0) S.V[l][row] = s;
        __syncthreads();
    }

    if (!GRAD) {
        if (tid < 64) {
            float zh = 0.f;
#pragma unroll
            for (int l = 0; l < NT; ++l) zh = fmaf(INVF[l], S.V[l][tid], zh);
            out[(size_t)b * 512 + k * 64 + tid] = zh;
        }
        return;
    }

    if (tid < 64) {
        float zh = 0.f;
#pragma unroll
        for (int l = 0; l < NT; ++l) zh = fmaf(INVF[l], S.V[l][tid], zh);
        S.U[0][tid] = zh - S.zz[tid];
    }
    __syncthreads();

    // u series (T^T via colT)
    for (int j = 1; j < NT; ++j) {
        const f32x4* up = (const f32x4*)&S.U[j - 1][c0];
        f32x4 u0 = up[0], u1 = up[1], u2 = up[2], u3 = up[3];
        float s0 = 0.f, s1 = 0.f, s2 = 0.f, s3 = 0.f;
#pragma unroll
        for (int i = 0; i < 4; ++i) {
            s0 = fmaf(colT[i], u0[i], s0);
            s1 = fmaf(colT[4 + i], u1[i], s1);
            s2 = fmaf(colT[8 + i], u2[i], s2);
            s3 = fmaf(colT[12 + i], u3[i], s3);
        }
        float s = qsum4((s0 + s1) + (s2 + s3));
        if (p == 0) S.U[j][row] = s;
        __syncthreads();
    }

    // O[row][c0..c0+15] = sum_l W[l] * V[l][c]
    float W[NT];
#pragma unroll
    for (int l = 0; l < NT; ++l) {
        float w = 0.f;
#pragma unroll
        for (int j = 0; j < NT; ++j) w = fmaf(INVF[j + l + 1], S.U[j][row], w);
        W[l] = w;
    }
    float o[16];
#pragma unroll
    for (int i = 0; i < 16; ++i) o[i] = 0.f;
#pragma unroll
    for (int l = 0; l < NT; ++l) {
        const f32x4* vp = (const f32x4*)&S.V[l][c0];
        f32x4 a0 = vp[0], a1 = vp[1], a2 = vp[2], a3 = vp[3];
        float w = W[l];
#pragma unroll
        for (int i = 0; i < 4; ++i) {
            o[i]      = fmaf(w, a0[i], o[i]);
            o[4 + i]  = fmaf(w, a1[i], o[4 + i]);
            o[8 + i]  = fmaf(w, a2[i], o[8 + i]);
            o[12 + i] = fmaf(w, a3[i], o[12 + i]);
        }
    }
    __syncthreads();   // all V/U reads done before caller reuses shared mem
    uint_t ow[8];
#pragma unroll
    for (int i = 0; i < 8; ++i)
        ow[i] = (uint_t)f2b(o[2 * i]) | ((uint_t)f2b(o[2 * i + 1]) << 16);
    uint4* op = (uint4*)(TO + (size_t)bid * 4096 + row * 64 + c0);
    op[0] = make_uint4(ow[0], ow[1], ow[2], ow[3]);
    op[1] = make_uint4(ow[4], ow[5], ow[6], ow[7]);
}

// --- fused dispatch: krylov<6> (2048 wgs) -> gemm2 partials (256) -> fista -
__global__ __launch_bounds__(256) void kgf_k(ushort_t* __restrict__ TO,
                                             const ushort_t* __restrict__ psiB,
                                             const float* __restrict__ z0,
                                             const float* __restrict__ z1,
                                             float* __restrict__ gpart,
                                             float* __restrict__ cb,
                                             float* __restrict__ yb,
                                             ushort_t* __restrict__ cbf,
                                             ushort_t* __restrict__ ybf,
                                             uint_t* __restrict__ cnt,
                                             int iter) {
    __shared__ __align__(16) FusedSm sm;
    int wg = blockIdx.x, tid = threadIdx.x;

    // phase 1: krylov gradient for this wg's (b,k); writes O over T
    kry_one<6, true>(wg, TO, z0, z1, nullptr, sm.kry, tid);
    ticket_sig(&cnt[0], tid);
    if (wg >= 256) return;

    // phase 2 (wgs 0..255): gemm2 split-K partial (R5-measured-good shape)
    ticket_wait(&cnt[0], 2048u, tid);
    {
        int bt = wg & 3;
        int kc = wg >> 2;              // 0..63
        int k = kc >> 3;
        int uv0 = (kc & 7) * 512;
        int wave = tid >> 6, lane = tid & 63;
        int rowi = lane & 15, q = lane >> 4;

        f32x4 acc[4][4];
        const f32x4 zero = {0.f, 0.f, 0.f, 0.f};
        for (int ta = 0; ta < 4; ++ta)
            for (int tb = 0; tb < 4; ++tb) acc[ta][tb] = zero;

        for (int ks = 0; ks < 4; ++ks) {
            int off = uv0 + wave * 128 + ks * 32 + q * 8;
            bf16x8 a[4], bb[4];
            for (int ta = 0; ta < 4; ++ta)
                a[ta] = *(const bf16x8*)(psiB + (size_t)k * 262144 +
                                         (size_t)(ta * 16 + rowi) * 4096 + off);
            for (int tb = 0; tb < 4; ++tb)
                bb[tb] = *(const bf16x8*)(TO +
                                          (size_t)(bt * 64 + tb * 16 + rowi) * 32768 +
                                          k * 4096 + off);
            for (int ta = 0; ta < 4; ++ta)
                for (int tb = 0; tb < 4; ++tb)
                    acc[ta][tb] = __builtin_amdgcn_mfma_f32_16x16x32_bf16(
                        a[ta], bb[tb], acc[ta][tb], 0, 0, 0);
        }
        for (int w = 0; w < 4; ++w) {
            if (wave == w) {
                for (int ta = 0; ta < 4; ++ta)
                    for (int tb = 0; tb < 4; ++tb) {
                        float* dst = &sm.lg[(tb * 16 + rowi) * 68 + ta * 16 + q * 4];
                        if (w == 0) *(f32x4*)dst = acc[ta][tb];
                        else {
                            f32x4 t = *(const f32x4*)dst;
                            t += acc[ta][tb];
                            *(f32x4*)dst = t;
                        }
                    }
            }
            __syncthreads();
        }
        int b = tid >> 2, mq = tid & 3;
        float* gp = gpart + (size_t)kc * 16384 + (size_t)(bt * 64 + b) * 64 + mq * 16;
        const float* lp = &sm.lg[b * 68 + mq * 16];
        for (int i = 0; i < 4; ++i)
            *(f32x4*)(gp + 4 * i) = *(const f32x4*)(lp + 4 * i);
    }
    ticket_sig(&cnt[1], tid);
    if (wg >= 64) return;

    // phase 3 (wgs 0..63): fista prox (R5 fista_update shape)
    ticket_wait(&cnt[1], 256u, tid);
    {
        int idx = wg * 256 + tid;
        float a0 = 0.f, a1 = 0.f, a2 = 0.f, a3 = 0.f;
#pragma unroll
        for (int pp = 0; pp < 64; pp += 4) {
            a0 += gpart[(size_t)pp * 16384 + idx];
            a1 += gpart[(size_t)(pp + 1) * 16384 + idx];
            a2 += gpart[(size_t)(pp + 2) * 16384 + idx];
            a3 += gpart[(size_t)(pp + 3) * 16384 + idx];
        }
        float gv = (a0 + a1) + (a2 + a3);
        float t = 1.f;
        for (int s = 0; s < iter; ++s) t = 0.5f * (1.f + sqrtf(1.f + 4.f * t * t));
        float tn = 0.5f * (1.f + sqrtf(1.f + 4.f * t * t));
        float beta = (t - 1.f) / tn;
        float co = cb[idx], yo = yb[idx];
        float a = yo - 0.01f * gv;
        float thr = 0.01f * 0.05f;
        float cn = copysignf(fmaxf(fabsf(a) - thr, 0.f), a);
        float yn = cn + beta * (cn - co);
        cb[idx] = cn;
        yb[idx] = yn;
        cbf[idx] = f2b(cn);
        ybf[idx] = f2b(yn);
    }
}

// --- final apply: krylov<8>, fp32 out ---------------------------------------
__global__ __launch_bounds__(256) void apply_k(ushort_t* __restrict__ TO,
                                               const float* __restrict__ z0,
                                               const float* __restrict__ z1,
                                               float* __restrict__ out) {
    __shared__ KryS S;
    kry_one<8, false>(blockIdx.x, TO, z0, z1, out, S, threadIdx.x);
}

extern "C" void kernel_launch(void* const* d_in, const int* in_sizes, int n_in,
                              void* d_out, int out_size, void* d_ws, size_t ws_size,
                              hipStream_t stream) {
    const float* z0 = (const float*)d_in[0];
    const float* z1 = (const float*)d_in[1];
    const float* psi = (const float*)d_in[2];
    float* out = (float*)d_out;

    char* w = (char*)d_ws;
    ushort_t* TO    = (ushort_t*)(w);                 // 16,777,216  (T, then O)
    ushort_t* psiB  = (ushort_t*)(w + 16777216);      //  4,194,304
    ushort_t* psiT  = (ushort_t*)(w + 20971520);      //  4,194,304
    float*    gpart = (float*)(w + 25165824);         //  4,194,304  (64 partials)
    float*    cbuf  = (float*)(w + 29360128);         //     65,536
    float*    ybuf  = (float*)(w + 29425664);         //     65,536
    ushort_t* cbf   = (ushort_t*)(w + 29491200);      //     32,768
    ushort_t* ybf   = (ushort_t*)(w + 29523968);      //     32,768
    uint_t*   cnts  = (uint_t*)(w + 29556736);        //        256  (2 per iter)
    // total 29,556,992 B

    // zero c,y state (fp32+bf16) AND the per-iteration ticket counters
    hipMemsetAsync(w + 29360128, 0, 196864, stream);

    prep_k<<<1024, 256, 0, stream>>>(psi, psiB, psiT);

    for (int it = 0; it < 20; ++it) {
        gemm1_k<<<1024, 256, 0, stream>>>(ybf, psiT, TO);
        kgf_k<<<2048, 256, 0, stream>>>(TO, psiB, z0, z1, gpart, cbuf, ybuf,
                                        cbf, ybf, cnts + it * 2, it);
    }

    gemm1_k<<<1024, 256, 0, stream>>>(cbf, psiT, TO);
    apply_k<<<2048, 256, 0, stream>>>(TO, z0, z1, out);
}

// Round 9
// 1188.272 us; speedup vs baseline: 7.2999x; 7.2999x over previous
//
#include <hip/hip_runtime.h>
#include <hip/hip_bf16.h>

// ---------------------------------------------------------------------------
// TransportOperator: FISTA sparse coding through block-diag expm + transport.
// B=256, D=512, K=8, M=64, N=64.  20 FISTA iters, lr=0.01, lambda=0.05.
//
// R3/R4/R7/R8 lesson: ALL intra-kernel cross-wg sync (tickets, atomics,
// coop launch) loses badly; dispatch boundaries are the cheapest barrier.
// R9: cut nodes 84->64 with ZERO sync by fusing fista INTO gemm1:
//   gemm1f (512 wgs = j-window x all 256 b): each wg redundantly recomputes
//     the full fista prox from gpart[8 k-partials] + ping-pong (c,y) state
//     (bitwise-identical across wgs -> benign), stages y_bf16 in LDS, then
//     T = y*psi via MFMA with LDS-transpose epilogue.  use_c=1 for final.
//   krylov<6> grad (2048 wgs, T in regs, DPP quad-reduce) - unchanged R6.
//   gemm2b (256 wgs = 32 bt x 8 k, K=4096): 8 k-partials, no atomics.
// Final: gemm1f(use_c) + krylov<8> apply.
// ---------------------------------------------------------------------------

typedef __attribute__((ext_vector_type(8))) short bf16x8;
typedef __attribute__((ext_vector_type(4))) float f32x4;
typedef unsigned short ushort_t;
typedef unsigned int uint_t;

__device__ __constant__ float INVF[20] = {
    1.0f, 1.0f, 0.5f, 1.6666666666666666e-1f, 4.1666666666666664e-2f,
    8.333333333333333e-3f, 1.3888888888888889e-3f, 1.984126984126984e-4f,
    2.48015873015873e-5f, 2.7557319223985893e-6f, 2.755731922398589e-7f,
    2.505210838544172e-8f, 2.08767569878681e-9f, 1.6059043836821613e-10f,
    1.1470745597729725e-11f, 7.647163731819816e-13f, 4.779477332387385e-14f,
    2.8114572543455206e-15f, 1.5619206968586225e-16f, 8.22063524662433e-18f};

__device__ __forceinline__ ushort_t f2b(float x) {
    uint_t u = __float_as_uint(x);
    uint_t r = u + 0x7FFFu + ((u >> 16) & 1u);   // RNE
    return (ushort_t)(r >> 16);
}
__device__ __forceinline__ float b2f(ushort_t h) {
    return __uint_as_float((uint_t)h << 16);
}

// quad sum via DPP (VALU pipe, no LDS ops)
__device__ __forceinline__ float qsum4(float s) {
    int a = __builtin_amdgcn_update_dpp(0, __float_as_int(s), 0xB1, 0xF, 0xF, true);
    s += __int_as_float(a);                       // xor 1
    int b = __builtin_amdgcn_update_dpp(0, __float_as_int(s), 0x4E, 0xF, 0xF, true);
    s += __int_as_float(b);                       // xor 2
    return s;
}

// --- one-time: psi fp32 -> psiB [k][m][uv] bf16 and psiT [j=k*4096+uv][m] --
__global__ __launch_bounds__(256) void prep_k(const float* __restrict__ psi,
                                              ushort_t* __restrict__ psiB,
                                              ushort_t* __restrict__ psiT) {
    int base = blockIdx.x * 2048 + threadIdx.x;
    for (int i = 0; i < 8; ++i) {
        int e = base + i * 256;                // e in [0, 2097152)
        float v = psi[e];
        ushort_t h = f2b(v);
        psiB[e] = h;
        int k = e >> 18;
        int r = e & 262143;
        int m = r >> 12;
        int uv = r & 4095;
        psiT[(size_t)k * 262144 + (size_t)uv * 64 + m] = h;
    }
}

// --- GEMM1+FISTA fused.  grid 512 = one 64-j window x ALL 256 b. -----------
// Each wg: (1) fista prox for all 16384 (b,m) from gpart[8]+(c,y) ping-pong
// (redundant, bitwise-identical); stage y (or c if use_c) bf16 in LDS.
// (2) T[b][j0..j0+64) = y * psiT via MFMA.  (3) LDS-transpose epilogue.
__global__ __launch_bounds__(256) void gemm1f_k(const ushort_t* __restrict__ psiT,
                                                ushort_t* __restrict__ Tbf,
                                                const float* __restrict__ gpart,
                                                const float* __restrict__ c_r,
                                                const float* __restrict__ y_r,
                                                float* __restrict__ c_w,
                                                float* __restrict__ y_w,
                                                int it, int use_c) {
    __shared__ __align__(16) ushort_t Ls[256 * 72];   // stage y, then T^T
    int wg = blockIdx.x;
    int j0 = wg * 64;
    int tid = threadIdx.x;
    int wave = tid >> 6, lane = tid & 63;
    int rowi = lane & 15, q = lane >> 4;

    // hoist A-frags (psiT, tiny: 8 KB/wg) for latency overlap with fista
    bf16x8 afr[4][2];
    for (int ta = 0; ta < 4; ++ta)
        for (int ks = 0; ks < 2; ++ks)
            afr[ta][ks] = *(const bf16x8*)(psiT +
                          (size_t)(j0 + ta * 16 + rowi) * 64 + ks * 32 + q * 8);

    // ---- fista prox (redundant per wg; identical arithmetic) ----
    float t = 1.f;
    for (int s = 1; s < it; ++s) t = 0.5f * (1.f + sqrtf(1.f + 4.f * t * t));
    float tn = 0.5f * (1.f + sqrtf(1.f + 4.f * t * t));
    float beta = (t - 1.f) / tn;
    const float lr = 0.01f, thr = 0.01f * 0.05f;
    for (int s = 0; s < 16; ++s) {
        int e = s * 1024 + tid * 4;
        f32x4 g = {0.f, 0.f, 0.f, 0.f};
#pragma unroll
        for (int p = 0; p < 8; ++p)
            g += *(const f32x4*)(gpart + (size_t)p * 16384 + e);
        f32x4 co = *(const f32x4*)(c_r + e);
        f32x4 yo = *(const f32x4*)(y_r + e);
        f32x4 cn, yn;
#pragma unroll
        for (int i = 0; i < 4; ++i) {
            float a = yo[i] - lr * g[i];
            float c = copysignf(fmaxf(fabsf(a) - thr, 0.f), a);
            cn[i] = c;
            yn[i] = c + beta * (c - co[i]);
        }
        if (wg == 0) {
            *(f32x4*)(c_w + e) = cn;
            *(f32x4*)(y_w + e) = yn;
        }
        f32x4 sv = use_c ? cn : yn;
        int b = e >> 6, m = e & 63;
        uint2 pk = make_uint2((uint_t)f2b(sv[0]) | ((uint_t)f2b(sv[1]) << 16),
                              (uint_t)f2b(sv[2]) | ((uint_t)f2b(sv[3]) << 16));
        *(uint2*)&Ls[b * 72 + m] = pk;
    }
    __syncthreads();

    // ---- B-frags (y) from LDS; wave covers b-quarter 64 ----
    int b0w = wave * 64;
    bf16x8 bfr[4][2];
    for (int tb = 0; tb < 4; ++tb)
        for (int ks = 0; ks < 2; ++ks)
            bfr[tb][ks] = *(const bf16x8*)&Ls[(b0w + tb * 16 + rowi) * 72 +
                                              ks * 32 + q * 8];
    __syncthreads();   // frags in regs; LDS now reusable for transpose

    // ---- MFMA: D[row=j-frag][col=b-frag] ----
    f32x4 acc[4][4];
    const f32x4 zero = {0.f, 0.f, 0.f, 0.f};
    for (int ta = 0; ta < 4; ++ta)
        for (int tb = 0; tb < 4; ++tb) acc[ta][tb] = zero;
    for (int ks = 0; ks < 2; ++ks)
        for (int ta = 0; ta < 4; ++ta)
            for (int tb = 0; tb < 4; ++tb)
                acc[ta][tb] = __builtin_amdgcn_mfma_f32_16x16x32_bf16(
                    afr[ta][ks], bfr[tb][ks], acc[ta][tb], 0, 0, 0);

    // ---- transpose epilogue (swizzled, R2-proven) ----
    for (int ta = 0; ta < 4; ++ta)
        for (int tb = 0; tb < 4; ++tb) {
            int bl = b0w + tb * 16 + rowi;            // 0..255
            int jl = ta * 16 + q * 4;
            uint_t lo = (uint_t)f2b(acc[ta][tb][0]) | ((uint_t)f2b(acc[ta][tb][1]) << 16);
            uint_t hi = (uint_t)f2b(acc[ta][tb][2]) | ((uint_t)f2b(acc[ta][tb][3]) << 16);
            int idx = bl * 72 + ((((jl >> 3) + 2 * bl) & 7) << 3) + (jl & 7);
            *(uint2*)&Ls[idx] = make_uint2(lo, hi);
        }
    __syncthreads();
    for (int pass = 0; pass < 8; ++pass) {
        int b = pass * 32 + (tid >> 3);
        int ch = tid & 7;
        uint4 v = *(const uint4*)&Ls[b * 72 + ch * 8];
        int x = (ch - 2 * b) & 7;
        *(uint4*)(Tbf + (size_t)b * 32768 + j0 + x * 8) = v;
    }
}

// --- Krylov: per (b,k); T in registers; grad mode writes O over T. ---------
template <int NT>
__global__ __launch_bounds__(256) void krylov_k(ushort_t* __restrict__ Tbf,
                                                const float* __restrict__ z0,
                                                const float* __restrict__ z1,
                                                float* __restrict__ out) {
    __shared__ float V[NT][64];
    __shared__ float U[NT][64];
    __shared__ float zz[64];
    int bid = blockIdx.x;
    int b = bid >> 3, k = bid & 7;
    int tid = threadIdx.x;
    int row = tid >> 2, p = tid & 3, c0 = p * 16;
    bool grad = (out == nullptr);

    const ushort_t* tbase = Tbf + (size_t)bid * 4096;
    float rowT[16];
    {
        uint4 ra = *(const uint4*)(tbase + row * 64 + c0);
        uint4 rb = *(const uint4*)(tbase + row * 64 + c0 + 8);
        uint_t wv[8] = {ra.x, ra.y, ra.z, ra.w, rb.x, rb.y, rb.z, rb.w};
        for (int i = 0; i < 8; ++i) {
            rowT[2 * i]     = __uint_as_float(wv[i] << 16);
            rowT[2 * i + 1] = __uint_as_float(wv[i] & 0xFFFF0000u);
        }
    }
    float colT[16];
    if (grad) {
#pragma unroll
        for (int i = 0; i < 16; ++i) colT[i] = b2f(tbase[(c0 + i) * 64 + row]);
    }
    if (tid < 64) {
        V[0][tid] = z0[(size_t)b * 512 + k * 64 + tid];
        zz[tid]   = z1[(size_t)b * 512 + k * 64 + tid];
    }
    __syncthreads();

    for (int l = 1; l < NT; ++l) {
        const f32x4* vp = (const f32x4*)&V[l - 1][c0];
        f32x4 v0 = vp[0], v1 = vp[1], v2 = vp[2], v3 = vp[3];
        float s0 = 0.f, s1 = 0.f, s2 = 0.f, s3 = 0.f;
#pragma unroll
        for (int i = 0; i < 4; ++i) {
            s0 = fmaf(rowT[i], v0[i], s0);
            s1 = fmaf(rowT[4 + i], v1[i], s1);
            s2 = fmaf(rowT[8 + i], v2[i], s2);
            s3 = fmaf(rowT[12 + i], v3[i], s3);
        }
        float s = qsum4((s0 + s1) + (s2 + s3));
        if (p == 0) V[l][row] = s;
        __syncthreads();
    }

    if (!grad) {
        if (tid < 64) {
            float zh = 0.f;
#pragma unroll
            for (int l = 0; l < NT; ++l) zh = fmaf(INVF[l], V[l][tid], zh);
            out[(size_t)b * 512 + k * 64 + tid] = zh;
        }
        return;
    }

    if (tid < 64) {
        float zh = 0.f;
#pragma unroll
        for (int l = 0; l < NT; ++l) zh = fmaf(INVF[l], V[l][tid], zh);
        U[0][tid] = zh - zz[tid];
    }
    __syncthreads();

    for (int j = 1; j < NT; ++j) {
        const f32x4* up = (const f32x4*)&U[j - 1][c0];
        f32x4 u0 = up[0], u1 = up[1], u2 = up[2], u3 = up[3];
        float s0 = 0.f, s1 = 0.f, s2 = 0.f, s3 = 0.f;
#pragma unroll
        for (int i = 0; i < 4; ++i) {
            s0 = fmaf(colT[i], u0[i], s0);
            s1 = fmaf(colT[4 + i], u1[i], s1);
            s2 = fmaf(colT[8 + i], u2[i], s2);
            s3 = fmaf(colT[12 + i], u3[i], s3);
        }
        float s = qsum4((s0 + s1) + (s2 + s3));
        if (p == 0) U[j][row] = s;
        __syncthreads();
    }

    float W[NT];
#pragma unroll
    for (int l = 0; l < NT; ++l) {
        float w = 0.f;
#pragma unroll
        for (int j = 0; j < NT; ++j) w = fmaf(INVF[j + l + 1], U[j][row], w);
        W[l] = w;
    }
    float o[16];
#pragma unroll
    for (int i = 0; i < 16; ++i) o[i] = 0.f;
#pragma unroll
    for (int l = 0; l < NT; ++l) {
        const f32x4* vp = (const f32x4*)&V[l][c0];
        f32x4 a0 = vp[0], a1 = vp[1], a2 = vp[2], a3 = vp[3];
        float w = W[l];
#pragma unroll
        for (int i = 0; i < 4; ++i) {
            o[i]      = fmaf(w, a0[i], o[i]);
            o[4 + i]  = fmaf(w, a1[i], o[4 + i]);
            o[8 + i]  = fmaf(w, a2[i], o[8 + i]);
            o[12 + i] = fmaf(w, a3[i], o[12 + i]);
        }
    }
    uint_t ow[8];
#pragma unroll
    for (int i = 0; i < 8; ++i)
        ow[i] = (uint_t)f2b(o[2 * i]) | ((uint_t)f2b(o[2 * i + 1]) << 16);
    uint4* op = (uint4*)(Tbf + (size_t)bid * 4096 + row * 64 + c0);
    op[0] = make_uint4(ow[0], ow[1], ow[2], ow[3]);
    op[1] = make_uint4(ow[4], ow[5], ow[6], ow[7]);
}

// --- GEMM2b: gpart[k][b][m] = sum_uv O[b][k,uv] psiB[k][m][uv] -------------
// grid 256 = 32 bt (8 b) x 8 k; 4 waves split K=4096; 8 k-partials total.
__global__ __launch_bounds__(256) void gemm2b_k(const ushort_t* __restrict__ Obf,
                                                const ushort_t* __restrict__ psiB,
                                                float* __restrict__ gpart) {
    __shared__ float Lg[64 * 9];       // [m 64][b 8] pad 9
    int bt = blockIdx.x & 31;
    int k = blockIdx.x >> 5;
    int tid = threadIdx.x, wave = tid >> 6, lane = tid & 63;
    int rowi = lane & 15, q = lane >> 4;

    f32x4 acc[4];
    const f32x4 zero = {0.f, 0.f, 0.f, 0.f};
    for (int ta = 0; ta < 4; ++ta) acc[ta] = zero;

    int off0 = wave * 1024 + q * 8;
    const ushort_t* ob = Obf + (size_t)(bt * 8 + (rowi & 7)) * 32768 +
                         k * 4096 + off0;
    const ushort_t* pb = psiB + (size_t)k * 262144 + (size_t)rowi * 4096 + off0;
#pragma unroll 4
    for (int ks = 0; ks < 32; ++ks) {
        bf16x8 bb = *(const bf16x8*)(ob + ks * 32);
#pragma unroll
        for (int ta = 0; ta < 4; ++ta) {
            bf16x8 a = *(const bf16x8*)(pb + (size_t)ta * 65536 + ks * 32);
            acc[ta] = __builtin_amdgcn_mfma_f32_16x16x32_bf16(a, bb, acc[ta], 0, 0, 0);
        }
    }
    // inter-wave reduce; D[row = m-frag q*4+r][col = b-frag rowi (0..7 valid)]
    for (int w = 0; w < 4; ++w) {
        if (wave == w && rowi < 8) {
            for (int ta = 0; ta < 4; ++ta)
                for (int r = 0; r < 4; ++r) {
                    int m = ta * 16 + q * 4 + r;
                    if (w == 0) Lg[m * 9 + rowi] = acc[ta][r];
                    else        Lg[m * 9 + rowi] += acc[ta][r];
                }
        }
        __syncthreads();
    }
    {   // store 8 b x 64 m: thread -> 2 consecutive elements (same b)
        int e = tid * 2;
        int b = e >> 6, m = e & 63;
        float2 v = make_float2(Lg[m * 9 + b], Lg[(m + 1) * 9 + b]);
        *(float2*)(gpart + (size_t)k * 16384 + (size_t)(bt * 8 + b) * 64 + m) = v;
    }
}

extern "C" void kernel_launch(void* const* d_in, const int* in_sizes, int n_in,
                              void* d_out, int out_size, void* d_ws, size_t ws_size,
                              hipStream_t stream) {
    const float* z0 = (const float*)d_in[0];
    const float* z1 = (const float*)d_in[1];
    const float* psi = (const float*)d_in[2];
    float* out = (float*)d_out;

    char* w = (char*)d_ws;
    ushort_t* TO    = (ushort_t*)(w);                 // 16,777,216  (T, then O)
    ushort_t* psiB  = (ushort_t*)(w + 16777216);      //  4,194,304
    ushort_t* psiT  = (ushort_t*)(w + 20971520);      //  4,194,304
    float*    gpart = (float*)(w + 25165824);         //    524,288  (8 partials)
    float*    cA    = (float*)(w + 25690112);         //     65,536
    float*    yA    = (float*)(w + 25755648);         //     65,536
    float*    cB    = (float*)(w + 25821184);         //     65,536
    float*    yB    = (float*)(w + 25886720);         //     65,536
    // total 25,952,256 B

    // zero gpart + both (c,y) ping-pong buffers in one shot
    hipMemsetAsync(w + 25165824, 0, 786432, stream);

    prep_k<<<1024, 256, 0, stream>>>(psi, psiB, psiT);

    float* cbuf[2] = {cA, cB};
    float* ybuf[2] = {yA, yB};
    for (int it = 0; it < 20; ++it) {
        int r = it & 1, wr = r ^ 1;
        gemm1f_k<<<512, 256, 0, stream>>>(psiT, TO, gpart, cbuf[r], ybuf[r],
                                          cbuf[wr], ybuf[wr], it, 0);
        krylov_k<6><<<2048, 256, 0, stream>>>(TO, z0, z1, nullptr);
        gemm2b_k<<<256, 256, 0, stream>>>(TO, psiB, gpart);
    }

    // final: update #20 -> c_20, T = c_20 * psi, then apply
    gemm1f_k<<<512, 256, 0, stream>>>(psiT, TO, gpart, cbuf[0], ybuf[0],
                                      cbuf[1], ybuf[1], 20, 1);
    krylov_k<8><<<2048, 256, 0, stream>>>(TO, z0, z1, out);
}

// Round 10
// 1178.038 us; speedup vs baseline: 7.3634x; 1.0087x over previous
//
#include <hip/hip_runtime.h>
#include <hip/hip_bf16.h>

// ---------------------------------------------------------------------------
// TransportOperator: FISTA sparse coding through block-diag expm + transport.
// B=256, D=512, K=8, M=64, N=64.  20 FISTA iters, lr=0.01, lambda=0.05.
//
// Structure (R10): 3 nodes/iter, NO cross-wg sync (R3/R4/R7/R8: all sync
// schemes lose; dispatch boundary = cheapest barrier ~4.8us):
//   gemm1f (grid 1024 = 512 j-win x 2 b-half): fista prox recomputed
//     redundantly per wg from gpart[8 bf16 k-partials, [b][k][m]] (128 KB/wg)
//     + ping-pong (c,y); stage y bf16 in LDS; T = y*psi MFMA; transpose epi.
//   krylov<5> grad (2048 wgs): T in regs, DPP quad-reduce, O over T.
//   gemm2b (256 wgs x 512 thr, 8 waves): full-K=4096 per (bt8,k); LDS
//     wave-reduce; bf16 partial out, coalesced.
// Final: gemm1f(use_c) + krylov<8> apply (output err is final-apply bf16).
// prep_k also zeroes gpart/c/y (no memset node).  63 nodes total.
// ---------------------------------------------------------------------------

typedef __attribute__((ext_vector_type(8))) short bf16x8;
typedef __attribute__((ext_vector_type(4))) float f32x4;
typedef unsigned short ushort_t;
typedef unsigned int uint_t;

__device__ __constant__ float INVF[20] = {
    1.0f, 1.0f, 0.5f, 1.6666666666666666e-1f, 4.1666666666666664e-2f,
    8.333333333333333e-3f, 1.3888888888888889e-3f, 1.984126984126984e-4f,
    2.48015873015873e-5f, 2.7557319223985893e-6f, 2.755731922398589e-7f,
    2.505210838544172e-8f, 2.08767569878681e-9f, 1.6059043836821613e-10f,
    1.1470745597729725e-11f, 7.647163731819816e-13f, 4.779477332387385e-14f,
    2.8114572543455206e-15f, 1.5619206968586225e-16f, 8.22063524662433e-18f};

__device__ __forceinline__ ushort_t f2b(float x) {
    uint_t u = __float_as_uint(x);
    uint_t r = u + 0x7FFFu + ((u >> 16) & 1u);   // RNE
    return (ushort_t)(r >> 16);
}
__device__ __forceinline__ float b2f(ushort_t h) {
    return __uint_as_float((uint_t)h << 16);
}

// quad sum via DPP (VALU pipe, no LDS ops)
__device__ __forceinline__ float qsum4(float s) {
    int a = __builtin_amdgcn_update_dpp(0, __float_as_int(s), 0xB1, 0xF, 0xF, true);
    s += __int_as_float(a);                       // xor 1
    int b = __builtin_amdgcn_update_dpp(0, __float_as_int(s), 0x4E, 0xF, 0xF, true);
    s += __int_as_float(b);                       // xor 2
    return s;
}

// --- one-time: psi -> psiB [k][m][uv], psiT [j][m]; zero gpart/cA/yA -------
__global__ __launch_bounds__(256) void prep_k(const float* __restrict__ psi,
                                              ushort_t* __restrict__ psiB,
                                              ushort_t* __restrict__ psiT,
                                              uint4* __restrict__ zero_base) {
    if (blockIdx.x < 96) {   // zero 96*256*16 B = 393216 B (gpart+cA+yA)
        zero_base[blockIdx.x * 256 + threadIdx.x] = make_uint4(0, 0, 0, 0);
    }
    int base = blockIdx.x * 2048 + threadIdx.x;
    for (int i = 0; i < 8; ++i) {
        int e = base + i * 256;                // e in [0, 2097152)
        float v = psi[e];
        ushort_t h = f2b(v);
        psiB[e] = h;
        int k = e >> 18;
        int r = e & 262143;
        int m = r >> 12;
        int uv = r & 4095;
        psiT[(size_t)k * 262144 + (size_t)uv * 64 + m] = h;
    }
}

// --- GEMM1+FISTA fused.  grid 1024 = 512 j-windows x 2 b-halves. -----------
__global__ __launch_bounds__(256) void gemm1f_k(const ushort_t* __restrict__ psiT,
                                                ushort_t* __restrict__ Tbf,
                                                const ushort_t* __restrict__ gpart,
                                                const float* __restrict__ c_r,
                                                const float* __restrict__ y_r,
                                                float* __restrict__ c_w,
                                                float* __restrict__ y_w,
                                                int it, int use_c) {
    __shared__ __align__(16) ushort_t Ls[128 * 72];   // y stage, then T^T
    int wg = blockIdx.x;
    int j0 = (wg & 511) * 64;
    int bt = wg >> 9;                   // b-half 0/1
    int tid = threadIdx.x;
    int wave = tid >> 6, lane = tid & 63;
    int rowi = lane & 15, q = lane >> 4;

    // ---- fista prox for this b-half (redundant across j-windows) ----
    float t = 1.f;
    for (int s = 1; s < it; ++s) t = 0.5f * (1.f + sqrtf(1.f + 4.f * t * t));
    float tn = 0.5f * (1.f + sqrtf(1.f + 4.f * t * t));
    float beta = (t - 1.f) / tn;
    const float lr = 0.01f, thr = 0.01f * 0.05f;
    bool writer = ((wg & 511) == 0);
    for (int s = 0; s < 8; ++s) {
        int e = bt * 8192 + s * 1024 + tid * 4;       // global (b,m) idx
        int b = e >> 6, m4 = e & 63;
        f32x4 g = {0.f, 0.f, 0.f, 0.f};
#pragma unroll
        for (int p = 0; p < 8; ++p) {
            uint2 pk = *(const uint2*)(gpart + (size_t)(b * 8 + p) * 64 + m4);
            g[0] += b2f((ushort_t)(pk.x & 0xFFFF));
            g[1] += b2f((ushort_t)(pk.x >> 16));
            g[2] += b2f((ushort_t)(pk.y & 0xFFFF));
            g[3] += b2f((ushort_t)(pk.y >> 16));
        }
        f32x4 co = *(const f32x4*)(c_r + e);
        f32x4 yo = *(const f32x4*)(y_r + e);
        f32x4 cn, yn;
#pragma unroll
        for (int i = 0; i < 4; ++i) {
            float a = yo[i] - lr * g[i];
            float c = copysignf(fmaxf(fabsf(a) - thr, 0.f), a);
            cn[i] = c;
            yn[i] = c + beta * (c - co[i]);
        }
        if (writer) {
            *(f32x4*)(c_w + e) = cn;
            *(f32x4*)(y_w + e) = yn;
        }
        f32x4 sv = use_c ? cn : yn;
        int bl = b - bt * 128;
        uint2 pk = make_uint2((uint_t)f2b(sv[0]) | ((uint_t)f2b(sv[1]) << 16),
                              (uint_t)f2b(sv[2]) | ((uint_t)f2b(sv[3]) << 16));
        *(uint2*)&Ls[bl * 72 + m4] = pk;
    }
    __syncthreads();

    // ---- frags: A = psiT j-window, B = y from LDS (wave covers 32 b) ----
    int b0w = wave * 32;                              // local b base
    bf16x8 afr[4][2], bfr[2][2];
    for (int ta = 0; ta < 4; ++ta)
        for (int ks = 0; ks < 2; ++ks)
            afr[ta][ks] = *(const bf16x8*)(psiT +
                          (size_t)(j0 + ta * 16 + rowi) * 64 + ks * 32 + q * 8);
    for (int tb = 0; tb < 2; ++tb)
        for (int ks = 0; ks < 2; ++ks)
            bfr[tb][ks] = *(const bf16x8*)&Ls[(b0w + tb * 16 + rowi) * 72 +
                                              ks * 32 + q * 8];
    __syncthreads();   // frags in regs; LDS reusable

    f32x4 acc[4][2];
    const f32x4 zero = {0.f, 0.f, 0.f, 0.f};
    for (int ta = 0; ta < 4; ++ta)
        for (int tb = 0; tb < 2; ++tb) acc[ta][tb] = zero;
    for (int ks = 0; ks < 2; ++ks)
        for (int ta = 0; ta < 4; ++ta)
            for (int tb = 0; tb < 2; ++tb)
                acc[ta][tb] = __builtin_amdgcn_mfma_f32_16x16x32_bf16(
                    afr[ta][ks], bfr[tb][ks], acc[ta][tb], 0, 0, 0);

    // ---- transpose epilogue (swizzled, R2-proven) ----
    for (int ta = 0; ta < 4; ++ta)
        for (int tb = 0; tb < 2; ++tb) {
            int bl = b0w + tb * 16 + rowi;            // local b 0..127
            int jl = ta * 16 + q * 4;
            uint_t lo = (uint_t)f2b(acc[ta][tb][0]) | ((uint_t)f2b(acc[ta][tb][1]) << 16);
            uint_t hi = (uint_t)f2b(acc[ta][tb][2]) | ((uint_t)f2b(acc[ta][tb][3]) << 16);
            int idx = bl * 72 + ((((jl >> 3) + 2 * bl) & 7) << 3) + (jl & 7);
            *(uint2*)&Ls[idx] = make_uint2(lo, hi);
        }
    __syncthreads();
    for (int pass = 0; pass < 4; ++pass) {
        int b = pass * 32 + (tid >> 3);               // local b
        int ch = tid & 7;
        uint4 v = *(const uint4*)&Ls[b * 72 + ch * 8];
        int x = (ch - 2 * b) & 7;
        *(uint4*)(Tbf + (size_t)(bt * 128 + b) * 32768 + j0 + x * 8) = v;
    }
}

// --- Krylov: per (b,k); T in registers; grad mode writes O over T. ---------
template <int NT>
__global__ __launch_bounds__(256) void krylov_k(ushort_t* __restrict__ Tbf,
                                                const float* __restrict__ z0,
                                                const float* __restrict__ z1,
                                                float* __restrict__ out) {
    __shared__ float V[NT][64];
    __shared__ float U[NT][64];
    __shared__ float zz[64];
    int bid = blockIdx.x;
    int b = bid >> 3, k = bid & 7;
    int tid = threadIdx.x;
    int row = tid >> 2, p = tid & 3, c0 = p * 16;
    bool grad = (out == nullptr);

    const ushort_t* tbase = Tbf + (size_t)bid * 4096;
    float rowT[16];
    {
        uint4 ra = *(const uint4*)(tbase + row * 64 + c0);
        uint4 rb = *(const uint4*)(tbase + row * 64 + c0 + 8);
        uint_t wv[8] = {ra.x, ra.y, ra.z, ra.w, rb.x, rb.y, rb.z, rb.w};
        for (int i = 0; i < 8; ++i) {
            rowT[2 * i]     = __uint_as_float(wv[i] << 16);
            rowT[2 * i + 1] = __uint_as_float(wv[i] & 0xFFFF0000u);
        }
    }
    float colT[16];
    if (grad) {
#pragma unroll
        for (int i = 0; i < 16; ++i) colT[i] = b2f(tbase[(c0 + i) * 64 + row]);
    }
    if (tid < 64) {
        V[0][tid] = z0[(size_t)b * 512 + k * 64 + tid];
        zz[tid]   = z1[(size_t)b * 512 + k * 64 + tid];
    }
    __syncthreads();

    for (int l = 1; l < NT; ++l) {
        const f32x4* vp = (const f32x4*)&V[l - 1][c0];
        f32x4 v0 = vp[0], v1 = vp[1], v2 = vp[2], v3 = vp[3];
        float s0 = 0.f, s1 = 0.f, s2 = 0.f, s3 = 0.f;
#pragma unroll
        for (int i = 0; i < 4; ++i) {
            s0 = fmaf(rowT[i], v0[i], s0);
            s1 = fmaf(rowT[4 + i], v1[i], s1);
            s2 = fmaf(rowT[8 + i], v2[i], s2);
            s3 = fmaf(rowT[12 + i], v3[i], s3);
        }
        float s = qsum4((s0 + s1) + (s2 + s3));
        if (p == 0) V[l][row] = s;
        __syncthreads();
    }

    if (!grad) {
        if (tid < 64) {
            float zh = 0.f;
#pragma unroll
            for (int l = 0; l < NT; ++l) zh = fmaf(INVF[l], V[l][tid], zh);
            out[(size_t)b * 512 + k * 64 + tid] = zh;
        }
        return;
    }

    if (tid < 64) {
        float zh = 0.f;
#pragma unroll
        for (int l = 0; l < NT; ++l) zh = fmaf(INVF[l], V[l][tid], zh);
        U[0][tid] = zh - zz[tid];
    }
    __syncthreads();

    for (int j = 1; j < NT; ++j) {
        const f32x4* up = (const f32x4*)&U[j - 1][c0];
        f32x4 u0 = up[0], u1 = up[1], u2 = up[2], u3 = up[3];
        float s0 = 0.f, s1 = 0.f, s2 = 0.f, s3 = 0.f;
#pragma unroll
        for (int i = 0; i < 4; ++i) {
            s0 = fmaf(colT[i], u0[i], s0);
            s1 = fmaf(colT[4 + i], u1[i], s1);
            s2 = fmaf(colT[8 + i], u2[i], s2);
            s3 = fmaf(colT[12 + i], u3[i], s3);
        }
        float s = qsum4((s0 + s1) + (s2 + s3));
        if (p == 0) U[j][row] = s;
        __syncthreads();
    }

    float W[NT];
#pragma unroll
    for (int l = 0; l < NT; ++l) {
        float w = 0.f;
#pragma unroll
        for (int j = 0; j < NT; ++j) w = fmaf(INVF[j + l + 1], U[j][row], w);
        W[l] = w;
    }
    float o[16];
#pragma unroll
    for (int i = 0; i < 16; ++i) o[i] = 0.f;
#pragma unroll
    for (int l = 0; l < NT; ++l) {
        const f32x4* vp = (const f32x4*)&V[l][c0];
        f32x4 a0 = vp[0], a1 = vp[1], a2 = vp[2], a3 = vp[3];
        float w = W[l];
#pragma unroll
        for (int i = 0; i < 4; ++i) {
            o[i]      = fmaf(w, a0[i], o[i]);
            o[4 + i]  = fmaf(w, a1[i], o[4 + i]);
            o[8 + i]  = fmaf(w, a2[i], o[8 + i]);
            o[12 + i] = fmaf(w, a3[i], o[12 + i]);
        }
    }
    uint_t ow[8];
#pragma unroll
    for (int i = 0; i < 8; ++i)
        ow[i] = (uint_t)f2b(o[2 * i]) | ((uint_t)f2b(o[2 * i + 1]) << 16);
    uint4* op = (uint4*)(Tbf + (size_t)bid * 4096 + row * 64 + c0);
    op[0] = make_uint4(ow[0], ow[1], ow[2], ow[3]);
    op[1] = make_uint4(ow[4], ow[5], ow[6], ow[7]);
}

// --- GEMM2b: gpart[b][k][m] (bf16) = sum_uv O[b][k,uv] psiB[k][m][uv] ------
// grid 256 = 32 bt (8 b) x 8 k; 512 threads = 8 waves, K=512 each.
__global__ __launch_bounds__(512) void gemm2b_k(const ushort_t* __restrict__ Obf,
                                                const ushort_t* __restrict__ psiB,
                                                ushort_t* __restrict__ gpart) {
    __shared__ float Lg[8 * 520];      // [wave][b*64+m] pad 520
    int bt = blockIdx.x & 31;
    int k = blockIdx.x >> 5;
    int tid = threadIdx.x, wave = tid >> 6, lane = tid & 63;
    int rowi = lane & 15, q = lane >> 4;

    f32x4 acc[4];
    const f32x4 zero = {0.f, 0.f, 0.f, 0.f};
    for (int ta = 0; ta < 4; ++ta) acc[ta] = zero;

    int off0 = wave * 512 + q * 8;
    const ushort_t* ob = Obf + (size_t)(bt * 8 + (rowi & 7)) * 32768 +
                         k * 4096 + off0;
    const ushort_t* pb = psiB + (size_t)k * 262144 + (size_t)rowi * 4096 + off0;
#pragma unroll 4
    for (int ks = 0; ks < 16; ++ks) {
        bf16x8 bb = *(const bf16x8*)(ob + ks * 32);
#pragma unroll
        for (int ta = 0; ta < 4; ++ta) {
            bf16x8 a = *(const bf16x8*)(pb + (size_t)ta * 65536 + ks * 32);
            acc[ta] = __builtin_amdgcn_mfma_f32_16x16x32_bf16(a, bb, acc[ta], 0, 0, 0);
        }
    }
    // wave partials -> LDS; D[row=m-frag q*4+r][col=b-frag rowi (0..7 valid)]
    if (rowi < 8) {
        for (int ta = 0; ta < 4; ++ta)
            for (int r = 0; r < 4; ++r) {
                int m = ta * 16 + q * 4 + r;
                Lg[wave * 520 + rowi * 64 + m] = acc[ta][r];
            }
    }
    __syncthreads();
    {   // reduce 8 waves; coalesced bf16 store to gpart[b][k][m]
        int b = tid >> 6, m = tid & 63;
        float s = 0.f;
#pragma unroll
        for (int w = 0; w < 8; ++w) s += Lg[w * 520 + tid];
        gpart[(size_t)(bt * 8 + b) * 512 + k * 64 + m] = f2b(s);
    }
}

extern "C" void kernel_launch(void* const* d_in, const int* in_sizes, int n_in,
                              void* d_out, int out_size, void* d_ws, size_t ws_size,
                              hipStream_t stream) {
    const float* z0 = (const float*)d_in[0];
    const float* z1 = (const float*)d_in[1];
    const float* psi = (const float*)d_in[2];
    float* out = (float*)d_out;

    char* w = (char*)d_ws;
    ushort_t* TO    = (ushort_t*)(w);                 // 16,777,216  (T, then O)
    ushort_t* psiB  = (ushort_t*)(w + 16777216);      //  4,194,304
    ushort_t* psiT  = (ushort_t*)(w + 20971520);      //  4,194,304
    ushort_t* gpart = (ushort_t*)(w + 25165824);      //    262,144  bf16 [b][k][m]
    float*    cA    = (float*)(w + 25427968);         //     65,536
    float*    yA    = (float*)(w + 25493504);         //     65,536
    float*    cB    = (float*)(w + 25559040);         //     65,536
    float*    yB    = (float*)(w + 25624576);         //     65,536
    // zero region = gpart+cA+yA = 393,216 B, handled by prep_k

    prep_k<<<1024, 256, 0, stream>>>(psi, psiB, psiT, (uint4*)(w + 25165824));

    float* cbuf[2] = {cA, cB};
    float* ybuf[2] = {yA, yB};
    for (int it = 0; it < 20; ++it) {
        int r = it & 1, wr = r ^ 1;
        gemm1f_k<<<1024, 256, 0, stream>>>(psiT, TO, gpart, cbuf[r], ybuf[r],
                                           cbuf[wr], ybuf[wr], it, 0);
        krylov_k<5><<<2048, 256, 0, stream>>>(TO, z0, z1, nullptr);
        gemm2b_k<<<256, 512, 0, stream>>>(TO, psiB, gpart);
    }

    // final: prox #20 -> c_20 (use_c), T = c_20*psi, then apply
    gemm1f_k<<<1024, 256, 0, stream>>>(psiT, TO, gpart, cbuf[0], ybuf[0],
                                       cbuf[1], ybuf[1], 20, 1);
    krylov_k<8><<<2048, 256, 0, stream>>>(TO, z0, z1, out);
}

// Round 11
// 847.034 us; speedup vs baseline: 10.2408x; 1.3908x over previous
//
#include <hip/hip_runtime.h>
#include <hip/hip_bf16.h>

// ---------------------------------------------------------------------------
// TransportOperator: FISTA sparse coding through block-diag expm + transport.
// B=256, D=512, K=8, M=64, N=64.  20 FISTA iters, lr=0.01, lambda=0.05.
//
// R11 = R6 champion structure (best measured: 865us) + validated micro-wins:
//   krylov<5> grad (R10-validated numerics), memset folded into prep_k.
// Structure per iter (4 nodes; all cross-wg sync schemes measured worse:
// R3 ticket-tail, R4 atomic fan-in, R7 coop-launch reject, R8 spin-thrash;
// 3-node fusions R9/R10 lose on traffic/AI -- see journal):
//   gemm1 (1024 wgs): T = y*psi, MFMA, swizzled LDS-transpose epilogue.
//   krylov<5> (2048 wgs): per-(b,k), T in regs, DPP quad-reduce, O over T.
//   gemm2 (256 wgs): 64 split-K fp32 partials, MFMA, LDS reduce, no atomics.
//   fista (64 wgs): reduce 64 partials + prox; writes fp32 state + bf16 y/c.
// Final: gemm1 + krylov<8> apply (output error is final-apply bf16-bound).
// ---------------------------------------------------------------------------

typedef __attribute__((ext_vector_type(8))) short bf16x8;
typedef __attribute__((ext_vector_type(4))) float f32x4;
typedef unsigned short ushort_t;
typedef unsigned int uint_t;

__device__ __constant__ float INVF[20] = {
    1.0f, 1.0f, 0.5f, 1.6666666666666666e-1f, 4.1666666666666664e-2f,
    8.333333333333333e-3f, 1.3888888888888889e-3f, 1.984126984126984e-4f,
    2.48015873015873e-5f, 2.7557319223985893e-6f, 2.755731922398589e-7f,
    2.505210838544172e-8f, 2.08767569878681e-9f, 1.6059043836821613e-10f,
    1.1470745597729725e-11f, 7.647163731819816e-13f, 4.779477332387385e-14f,
    2.8114572543455206e-15f, 1.5619206968586225e-16f, 8.22063524662433e-18f};

__device__ __forceinline__ ushort_t f2b(float x) {
    uint_t u = __float_as_uint(x);
    uint_t r = u + 0x7FFFu + ((u >> 16) & 1u);   // RNE
    return (ushort_t)(r >> 16);
}
__device__ __forceinline__ float b2f(ushort_t h) {
    return __uint_as_float((uint_t)h << 16);
}

// quad sum via DPP (VALU pipe, no LDS ops)
__device__ __forceinline__ float qsum4(float s) {
    int a = __builtin_amdgcn_update_dpp(0, __float_as_int(s), 0xB1, 0xF, 0xF, true);
    s += __int_as_float(a);                       // xor 1
    int b = __builtin_amdgcn_update_dpp(0, __float_as_int(s), 0x4E, 0xF, 0xF, true);
    s += __int_as_float(b);                       // xor 2
    return s;
}

// --- one-time: psi -> psiB [k][m][uv], psiT [j][m]; zero c/y state ---------
__global__ __launch_bounds__(256) void prep_k(const float* __restrict__ psi,
                                              ushort_t* __restrict__ psiB,
                                              ushort_t* __restrict__ psiT,
                                              uint4* __restrict__ zero_base) {
    if (blockIdx.x < 48)   // zero 48*256*16 B = 196608 B (c,y fp32 + bf16)
        zero_base[blockIdx.x * 256 + threadIdx.x] = make_uint4(0, 0, 0, 0);
    int base = blockIdx.x * 2048 + threadIdx.x;
    for (int i = 0; i < 8; ++i) {
        int e = base + i * 256;                // e in [0, 2097152)
        float v = psi[e];
        ushort_t h = f2b(v);
        psiB[e] = h;
        int k = e >> 18;
        int r = e & 262143;
        int m = r >> 12;
        int uv = r & 4095;
        psiT[(size_t)k * 262144 + (size_t)uv * 64 + m] = h;
    }
}

// --- GEMM1: T[b][j] = sum_m y[b,m] * psiT[j,m].  D-rows <-> j. -------------
// grid 1024 = 512 j-windows x 2 b-halves (128 b).  18 KB LDS.
__global__ __launch_bounds__(256) void gemm1_k(const ushort_t* __restrict__ ybf,
                                               const ushort_t* __restrict__ psiT,
                                               ushort_t* __restrict__ Tbf) {
    __shared__ __align__(16) ushort_t Ls[128 * 72];   // [b 128][j 64] swizzled
    int wg = blockIdx.x;
    int j0 = (wg & 511) * 64;
    int bt = wg >> 9;                   // 0..1
    int tid = threadIdx.x;
    int wave = tid >> 6, lane = tid & 63;
    int rowi = lane & 15, q = lane >> 4;
    int b0w = bt * 128 + wave * 32;

    f32x4 acc[4][2];
    const f32x4 zero = {0.f, 0.f, 0.f, 0.f};
    for (int ta = 0; ta < 4; ++ta)
        for (int tb = 0; tb < 2; ++tb) acc[ta][tb] = zero;

    for (int ks = 0; ks < 2; ++ks) {
        bf16x8 a[4], bb[2];
        for (int ta = 0; ta < 4; ++ta)
            a[ta] = *(const bf16x8*)(psiT + (size_t)(j0 + ta * 16 + rowi) * 64 +
                                     ks * 32 + q * 8);
        for (int tb = 0; tb < 2; ++tb)
            bb[tb] = *(const bf16x8*)(ybf + (size_t)(b0w + tb * 16 + rowi) * 64 +
                                      ks * 32 + q * 8);
        for (int ta = 0; ta < 4; ++ta)
            for (int tb = 0; tb < 2; ++tb)
                acc[ta][tb] = __builtin_amdgcn_mfma_f32_16x16x32_bf16(
                    a[ta], bb[tb], acc[ta][tb], 0, 0, 0);
    }
    for (int ta = 0; ta < 4; ++ta)
        for (int tb = 0; tb < 2; ++tb) {
            int bl = wave * 32 + tb * 16 + rowi;      // local b in [0,128)
            int jl = ta * 16 + q * 4;
            uint_t lo = (uint_t)f2b(acc[ta][tb][0]) | ((uint_t)f2b(acc[ta][tb][1]) << 16);
            uint_t hi = (uint_t)f2b(acc[ta][tb][2]) | ((uint_t)f2b(acc[ta][tb][3]) << 16);
            int idx = bl * 72 + ((((jl >> 3) + 2 * bl) & 7) << 3) + (jl & 7);
            *(uint2*)&Ls[idx] = make_uint2(lo, hi);
        }
    __syncthreads();
    for (int pass = 0; pass < 4; ++pass) {
        int b = pass * 32 + (tid >> 3);               // local b
        int ch = tid & 7;
        uint4 v = *(const uint4*)&Ls[b * 72 + ch * 8];
        int x = (ch - 2 * b) & 7;
        *(uint4*)(Tbf + (size_t)(bt * 128 + b) * 32768 + j0 + x * 8) = v;
    }
}

// --- Krylov: per (b,k); T in registers; grad mode writes O over T. ---------
template <int NT>
__global__ __launch_bounds__(256) void krylov_k(ushort_t* __restrict__ Tbf,
                                                const float* __restrict__ z0,
                                                const float* __restrict__ z1,
                                                float* __restrict__ out) {
    __shared__ float V[NT][64];
    __shared__ float U[NT][64];
    __shared__ float zz[64];
    int bid = blockIdx.x;
    int b = bid >> 3, k = bid & 7;
    int tid = threadIdx.x;
    int row = tid >> 2, p = tid & 3, c0 = p * 16;
    bool grad = (out == nullptr);

    const ushort_t* tbase = Tbf + (size_t)bid * 4096;
    float rowT[16];
    {
        uint4 ra = *(const uint4*)(tbase + row * 64 + c0);
        uint4 rb = *(const uint4*)(tbase + row * 64 + c0 + 8);
        uint_t wv[8] = {ra.x, ra.y, ra.z, ra.w, rb.x, rb.y, rb.z, rb.w};
        for (int i = 0; i < 8; ++i) {
            rowT[2 * i]     = __uint_as_float(wv[i] << 16);
            rowT[2 * i + 1] = __uint_as_float(wv[i] & 0xFFFF0000u);
        }
    }
    float colT[16];
    if (grad) {
#pragma unroll
        for (int i = 0; i < 16; ++i) colT[i] = b2f(tbase[(c0 + i) * 64 + row]);
    }
    if (tid < 64) {
        V[0][tid] = z0[(size_t)b * 512 + k * 64 + tid];
        zz[tid]   = z1[(size_t)b * 512 + k * 64 + tid];
    }
    __syncthreads();

    for (int l = 1; l < NT; ++l) {
        const f32x4* vp = (const f32x4*)&V[l - 1][c0];
        f32x4 v0 = vp[0], v1 = vp[1], v2 = vp[2], v3 = vp[3];
        float s0 = 0.f, s1 = 0.f, s2 = 0.f, s3 = 0.f;
#pragma unroll
        for (int i = 0; i < 4; ++i) {
            s0 = fmaf(rowT[i], v0[i], s0);
            s1 = fmaf(rowT[4 + i], v1[i], s1);
            s2 = fmaf(rowT[8 + i], v2[i], s2);
            s3 = fmaf(rowT[12 + i], v3[i], s3);
        }
        float s = qsum4((s0 + s1) + (s2 + s3));
        if (p == 0) V[l][row] = s;
        __syncthreads();
    }

    if (!grad) {
        if (tid < 64) {
            float zh = 0.f;
#pragma unroll
            for (int l = 0; l < NT; ++l) zh = fmaf(INVF[l], V[l][tid], zh);
            out[(size_t)b * 512 + k * 64 + tid] = zh;
        }
        return;
    }

    if (tid < 64) {
        float zh = 0.f;
#pragma unroll
        for (int l = 0; l < NT; ++l) zh = fmaf(INVF[l], V[l][tid], zh);
        U[0][tid] = zh - zz[tid];
    }
    __syncthreads();

    for (int j = 1; j < NT; ++j) {
        const f32x4* up = (const f32x4*)&U[j - 1][c0];
        f32x4 u0 = up[0], u1 = up[1], u2 = up[2], u3 = up[3];
        float s0 = 0.f, s1 = 0.f, s2 = 0.f, s3 = 0.f;
#pragma unroll
        for (int i = 0; i < 4; ++i) {
            s0 = fmaf(colT[i], u0[i], s0);
            s1 = fmaf(colT[4 + i], u1[i], s1);
            s2 = fmaf(colT[8 + i], u2[i], s2);
            s3 = fmaf(colT[12 + i], u3[i], s3);
        }
        float s = qsum4((s0 + s1) + (s2 + s3));
        if (p == 0) U[j][row] = s;
        __syncthreads();
    }

    float W[NT];
#pragma unroll
    for (int l = 0; l < NT; ++l) {
        float w = 0.f;
#pragma unroll
        for (int j = 0; j < NT; ++j) w = fmaf(INVF[j + l + 1], U[j][row], w);
        W[l] = w;
    }
    float o[16];
#pragma unroll
    for (int i = 0; i < 16; ++i) o[i] = 0.f;
#pragma unroll
    for (int l = 0; l < NT; ++l) {
        const f32x4* vp = (const f32x4*)&V[l][c0];
        f32x4 a0 = vp[0], a1 = vp[1], a2 = vp[2], a3 = vp[3];
        float w = W[l];
#pragma unroll
        for (int i = 0; i < 4; ++i) {
            o[i]      = fmaf(w, a0[i], o[i]);
            o[4 + i]  = fmaf(w, a1[i], o[4 + i]);
            o[8 + i]  = fmaf(w, a2[i], o[8 + i]);
            o[12 + i] = fmaf(w, a3[i], o[12 + i]);
        }
    }
    uint_t ow[8];
#pragma unroll
    for (int i = 0; i < 8; ++i)
        ow[i] = (uint_t)f2b(o[2 * i]) | ((uint_t)f2b(o[2 * i + 1]) << 16);
    uint4* op = (uint4*)(Tbf + (size_t)bid * 4096 + row * 64 + c0);
    op[0] = make_uint4(ow[0], ow[1], ow[2], ow[3]);
    op[1] = make_uint4(ow[4], ow[5], ow[6], ow[7]);
}

// --- GEMM2: gpart[kc][b][m] = sum_{uv in chunk} O[b][.] psiB[m][.] ---------
// grid 256 = 4 bt x 64 kc; 4 waves split the 512-long K-chunk; LDS reduce.
__global__ __launch_bounds__(256) void gemm2_k(const ushort_t* __restrict__ Obf,
                                               const ushort_t* __restrict__ psiB,
                                               float* __restrict__ gpart) {
    __shared__ __align__(16) float Lg[64 * 68];    // [b 64][m 64] stride 68
    int bt = blockIdx.x & 3;
    int kc = blockIdx.x >> 2;          // 0..63
    int k = kc >> 3;
    int uv0 = (kc & 7) * 512;
    int tid = threadIdx.x, wave = tid >> 6, lane = tid & 63;
    int rowi = lane & 15, q = lane >> 4;

    f32x4 acc[4][4];
    const f32x4 zero = {0.f, 0.f, 0.f, 0.f};
    for (int ta = 0; ta < 4; ++ta)
        for (int tb = 0; tb < 4; ++tb) acc[ta][tb] = zero;

    for (int ks = 0; ks < 4; ++ks) {
        int off = uv0 + wave * 128 + ks * 32 + q * 8;
        bf16x8 a[4], bb[4];
        for (int ta = 0; ta < 4; ++ta)
            a[ta] = *(const bf16x8*)(psiB + (size_t)k * 262144 +
                                     (size_t)(ta * 16 + rowi) * 4096 + off);
        for (int tb = 0; tb < 4; ++tb)
            bb[tb] = *(const bf16x8*)(Obf +
                                      (size_t)(bt * 64 + tb * 16 + rowi) * 32768 +
                                      k * 4096 + off);
        for (int ta = 0; ta < 4; ++ta)
            for (int tb = 0; tb < 4; ++tb)
                acc[ta][tb] = __builtin_amdgcn_mfma_f32_16x16x32_bf16(
                    a[ta], bb[tb], acc[ta][tb], 0, 0, 0);
    }
    for (int w = 0; w < 4; ++w) {
        if (wave == w) {
            for (int ta = 0; ta < 4; ++ta)
                for (int tb = 0; tb < 4; ++tb) {
                    float* dst = &Lg[(tb * 16 + rowi) * 68 + ta * 16 + q * 4];
                    if (w == 0) *(f32x4*)dst = acc[ta][tb];
                    else {
                        f32x4 t = *(const f32x4*)dst;
                        t += acc[ta][tb];
                        *(f32x4*)dst = t;
                    }
                }
        }
        __syncthreads();
    }
    int b = tid >> 2, mq = tid & 3;
    float* gp = gpart + (size_t)kc * 16384 + (size_t)(bt * 64 + b) * 64 + mq * 16;
    const float* lp = &Lg[b * 68 + mq * 16];
    for (int i = 0; i < 4; ++i)
        *(f32x4*)(gp + 4 * i) = *(const f32x4*)(lp + 4 * i);
}

// --- FISTA: reduce 64 partials + prox step; maintain fp32 + bf16 state -----
__global__ __launch_bounds__(256) void fista_update(const float* __restrict__ gpart,
                                                    float* __restrict__ cb,
                                                    float* __restrict__ yb,
                                                    ushort_t* __restrict__ cbf,
                                                    ushort_t* __restrict__ ybf,
                                                    int iter) {
    int idx = blockIdx.x * 256 + threadIdx.x;
    float a0 = 0.f, a1 = 0.f, a2 = 0.f, a3 = 0.f;
#pragma unroll
    for (int p = 0; p < 64; p += 4) {
        a0 += gpart[(size_t)p * 16384 + idx];
        a1 += gpart[(size_t)(p + 1) * 16384 + idx];
        a2 += gpart[(size_t)(p + 2) * 16384 + idx];
        a3 += gpart[(size_t)(p + 3) * 16384 + idx];
    }
    float gv = (a0 + a1) + (a2 + a3);
    float t = 1.f;
    for (int s = 0; s < iter; ++s) t = 0.5f * (1.f + sqrtf(1.f + 4.f * t * t));
    float tn = 0.5f * (1.f + sqrtf(1.f + 4.f * t * t));
    float beta = (t - 1.f) / tn;
    float co = cb[idx], yo = yb[idx];
    float a = yo - 0.01f * gv;
    float thr = 0.01f * 0.05f;
    float cn = copysignf(fmaxf(fabsf(a) - thr, 0.f), a);
    float yn = cn + beta * (cn - co);
    cb[idx] = cn;
    yb[idx] = yn;
    cbf[idx] = f2b(cn);
    ybf[idx] = f2b(yn);
}

extern "C" void kernel_launch(void* const* d_in, const int* in_sizes, int n_in,
                              void* d_out, int out_size, void* d_ws, size_t ws_size,
                              hipStream_t stream) {
    const float* z0 = (const float*)d_in[0];
    const float* z1 = (const float*)d_in[1];
    const float* psi = (const float*)d_in[2];
    float* out = (float*)d_out;

    char* w = (char*)d_ws;
    ushort_t* TO    = (ushort_t*)(w);                 // 16,777,216  (T, then O)
    ushort_t* psiB  = (ushort_t*)(w + 16777216);      //  4,194,304
    ushort_t* psiT  = (ushort_t*)(w + 20971520);      //  4,194,304
    float*    gpart = (float*)(w + 25165824);         //  4,194,304  (64 partials)
    float*    cbuf  = (float*)(w + 29360128);         //     65,536
    float*    ybuf  = (float*)(w + 29425664);         //     65,536
    ushort_t* cbf   = (ushort_t*)(w + 29491200);      //     32,768
    ushort_t* ybf   = (ushort_t*)(w + 29523968);      //     32,768
    // total 29,556,736 B

    // prep converts psi AND zeroes c/y state (196608 B) -- no memset node
    prep_k<<<1024, 256, 0, stream>>>(psi, psiB, psiT, (uint4*)(w + 29360128));

    for (int it = 0; it < 20; ++it) {
        gemm1_k<<<1024, 256, 0, stream>>>(ybf, psiT, TO);
        krylov_k<5><<<2048, 256, 0, stream>>>(TO, z0, z1, nullptr);
        gemm2_k<<<256, 256, 0, stream>>>(TO, psiB, gpart);
        fista_update<<<64, 256, 0, stream>>>(gpart, cbuf, ybuf, cbf, ybf, it);
    }

    gemm1_k<<<1024, 256, 0, stream>>>(cbf, psiT, TO);
    krylov_k<8><<<2048, 256, 0, stream>>>(TO, z0, z1, out);
}